// Round 4
// baseline (262.109 us; speedup 1.0000x reference)
//
#include <hip/hip_runtime.h>
#include <hip/hip_bf16.h>

#define FEAT    256
#define KDIM    512   // FEAT + EMBED
#define EMBED   256
#define BATCH   50000
#define NSAMP   25
#define N_NODES 100000
#define NAN_FILL 0.01f

#define NTILE   32    // batch items per block (LDS tile rows)
#define LSTRIDE 520   // shorts per LDS row: 512 + 8 pad (260 words == 4 mod 32)

#define FCONV_BLOCKS 12500          // N_NODES*FEAT / (256*8)
#define WCONV_BLOCKS 64             // EMBED*KDIM  / (256*8) = 131072/2048

typedef __attribute__((ext_vector_type(8))) short  short8;
typedef __attribute__((ext_vector_type(4))) float  floatx4;
typedef __attribute__((ext_vector_type(2))) float  float2v;
typedef __attribute__((ext_vector_type(4))) unsigned short ushort4v;
typedef __attribute__((ext_vector_type(4))) float  float4v;

__device__ inline unsigned short f2bf(float x) {
    __hip_bfloat16 h = __float2bfloat16(x);
    union { __hip_bfloat16 h; unsigned short u; } c; c.h = h;
    return c.u;
}

// ---- Stage 0 (merged): features f32 -> fp8 e4m3 table; W f32 -> bf16 ----
// HW packed conversion: v_cvt_pk_fp8_f32 = 2 elems/instr (was ~100s of cycles
// each via the __hip_fp8_e4m3 software constructor -> fconv was ~150us!).
__global__ __launch_bounds__(256) void conv_kernel(
    const float* __restrict__ F, unsigned char* __restrict__ F8,
    const float* __restrict__ W, unsigned short* __restrict__ Wb)
{
    if (blockIdx.x < FCONV_BLOCKS) {
        const size_t i = ((size_t)blockIdx.x * 256 + threadIdx.x) * 8;
        float4v a = *(const float4v*)(F + i);
        float4v b = *(const float4v*)(F + i + 4);
        int p0 = 0, p1 = 0;
        p0 = __builtin_amdgcn_cvt_pk_fp8_f32(a[0], a[1], p0, false);
        p0 = __builtin_amdgcn_cvt_pk_fp8_f32(a[2], a[3], p0, true);
        p1 = __builtin_amdgcn_cvt_pk_fp8_f32(b[0], b[1], p1, false);
        p1 = __builtin_amdgcn_cvt_pk_fp8_f32(b[2], b[3], p1, true);
        uint2 o; o.x = (unsigned)p0; o.y = (unsigned)p1;
        *(uint2*)(F8 + i) = o;
    } else {
        const size_t i = ((size_t)(blockIdx.x - FCONV_BLOCKS) * 256 + threadIdx.x) * 8;
        float4v a = *(const float4v*)(W + i);
        float4v b = *(const float4v*)(W + i + 4);
        ushort4v o0, o1;
        o0[0] = f2bf(a[0]); o0[1] = f2bf(a[1]); o0[2] = f2bf(a[2]); o0[3] = f2bf(a[3]);
        o1[0] = f2bf(b[0]); o1[1] = f2bf(b[1]); o1[2] = f2bf(b[2]); o1[3] = f2bf(b[3]);
        *(ushort4v*)(Wb + i) = o0;
        *(ushort4v*)(Wb + i + 4) = o1;
    }
}

// ---- Fused: gather+mean -> LDS tile -> MFMA GEMM -> ReLU -> out ----
// Block: 256 threads (4 waves), NTILE=32 batch items, 4 blocks/CU.
// Phase 1: wave stages 8 items: self row from f32 F (16B/lane), 25 neighbor
//          rows from fp8 F8 (4B/lane, HW packed cvt), bf16 into LDS [32][520].
// Phase 2: out[e,b] = relu(sum_k W[e,k]*C[b,k]); M=256 (wave covers 64 rows),
//          N=32 (2 x 16-col tiles), K=512. A from global (L2-resident), B from LDS.
// MFMA 16x16x32 bf16 layouts (guide-verified):
//   A: lane holds A[m=lane&15][k=(lane>>4)*8+j]; B: B[k=(lane>>4)*8+j][n=lane&15]
//   D: row=(lane>>4)*4+reg, col=lane&15
__global__ __launch_bounds__(256, 4) void enc_kernel(
    const float* __restrict__ F,            // [N_NODES, 256] f32
    const unsigned char* __restrict__ F8,   // [N_NODES, 256] fp8
    const unsigned short* __restrict__ Wb,  // [256, 512] bf16
    const int* __restrict__ nodes,
    const int* __restrict__ neigh,          // [BATCH, NSAMP]
    float* __restrict__ out)                // [256, BATCH] f32
{
    __shared__ unsigned short cl[NTILE * LSTRIDE];  // 33,280 B -> 4 blocks/CU

    const int lane = threadIdx.x & 63;
    const int wave = threadIdx.x >> 6;
    const int q = lane >> 4;
    const int r = lane & 15;
    const int nbase = blockIdx.x * NTILE;

    // ---- Phase 1: gather + mean into LDS ----
    for (int it = 0; it < NTILE / 4; ++it) {
        const int li = wave * (NTILE / 4) + it;     // LDS row 0..31
        int b = nbase + li;
        if (b >= BATCH) b = BATCH - 1;              // duplicate work, stores guarded

        const int node = nodes[b];                  // wave-uniform
        float4v sv = *(const float4v*)(F + (size_t)node * FEAT + lane * 4);

        const int* nb = neigh + (size_t)b * NSAMP;
        float s0 = 0.f, s1 = 0.f, s2 = 0.f, s3 = 0.f;
        #pragma unroll
        for (int j = 0; j < NSAMP; ++j) {
            const int idx = nb[j];                  // wave-uniform -> scalar load
            int wv = *(const int*)(F8 + (size_t)idx * FEAT + lane * 4);
            float2v lo = __builtin_amdgcn_cvt_pk_f32_fp8(wv, false);  // bytes 0,1
            float2v hi = __builtin_amdgcn_cvt_pk_f32_fp8(wv, true);   // bytes 2,3
            s0 += lo[0]; s1 += lo[1]; s2 += hi[0]; s3 += hi[1];
        }
        const float inv = 1.0f / NSAMP;
        float m0 = s0 * inv, m1 = s1 * inv, m2 = s2 * inv, m3 = s3 * inv;
        if (m0 != m0) m0 = NAN_FILL;
        if (m1 != m1) m1 = NAN_FILL;
        if (m2 != m2) m2 = NAN_FILL;
        if (m3 != m3) m3 = NAN_FILL;

        unsigned short* row = cl + li * LSTRIDE;
        ushort4v s; s[0] = f2bf(sv[0]); s[1] = f2bf(sv[1]); s[2] = f2bf(sv[2]); s[3] = f2bf(sv[3]);
        *(ushort4v*)(row + lane * 4) = s;
        ushort4v m; m[0] = f2bf(m0); m[1] = f2bf(m1); m[2] = f2bf(m2); m[3] = f2bf(m3);
        *(ushort4v*)(row + FEAT + lane * 4) = m;
    }
    __syncthreads();

    // ---- Phase 2: MFMA GEMM from LDS tile ----
    const int mbase = wave * 64;
    const short* Wp = (const short*)Wb;
    const short* cp = (const short*)cl;

    floatx4 acc[4][2] = {};

    for (int k = 0; k < KDIM; k += 32) {
        short8 afr[4], bfr[2];
        #pragma unroll
        for (int mt = 0; mt < 4; ++mt) {
            const short* p = Wp + (size_t)(mbase + mt * 16 + r) * KDIM + k + q * 8;
            afr[mt] = *(const short8*)p;
        }
        #pragma unroll
        for (int nt = 0; nt < 2; ++nt) {
            const short* p = cp + (nt * 16 + r) * LSTRIDE + k + q * 8;
            bfr[nt] = *(const short8*)p;
        }
        #pragma unroll
        for (int mt = 0; mt < 4; ++mt)
            #pragma unroll
            for (int nt = 0; nt < 2; ++nt)
                acc[mt][nt] = __builtin_amdgcn_mfma_f32_16x16x32_bf16(
                    afr[mt], bfr[nt], acc[mt][nt], 0, 0, 0);
    }

    // ---- Epilogue: ReLU + store ----
    #pragma unroll
    for (int mt = 0; mt < 4; ++mt) {
        #pragma unroll
        for (int nt = 0; nt < 2; ++nt) {
            const int col = nbase + nt * 16 + r;
            if (col < BATCH) {
                #pragma unroll
                for (int i = 0; i < 4; ++i) {
                    const int row = mbase + mt * 16 + q * 4 + i;
                    float v = acc[mt][nt][i];
                    out[(size_t)row * BATCH + col] = v > 0.f ? v : 0.f;
                }
            }
        }
    }
}

extern "C" void kernel_launch(void* const* d_in, const int* in_sizes, int n_in,
                              void* d_out, int out_size, void* d_ws, size_t ws_size,
                              hipStream_t stream) {
    const float* features = (const float*)d_in[0];   // [100000, 256] f32
    const float* weight   = (const float*)d_in[1];   // [256, 512] f32
    const int*   nodes    = (const int*)d_in[2];     // [50000]
    const int*   neigh    = (const int*)d_in[3];     // [50000, 25]
    float* out = (float*)d_out;                      // [256, 50000] f32

    unsigned char* F8  = (unsigned char*)d_ws;                           // 25.6 MB
    unsigned short* Wb = (unsigned short*)(F8 + (size_t)N_NODES * FEAT); // +0.25 MB

    conv_kernel<<<FCONV_BLOCKS + WCONV_BLOCKS, 256, 0, stream>>>(features, F8, weight, Wb);

    const int nblocks = (BATCH + NTILE - 1) / NTILE;  // 1563
    enc_kernel<<<nblocks, 256, 0, stream>>>(features, F8, Wb, nodes, neigh, out);
}